// Round 18
// baseline (108.076 us; speedup 1.0000x reference)
//
#include <hip/hip_runtime.h>

// Problem constants (match reference)
#define VOCABN 100
#define EMBEDN 16
#define STATEN 7
#define OUTN   10
#define BATCHN 4096
#define SEQT   512
#define L2E 1.44269504088896340736f

typedef float v2f __attribute__((ext_vector_type(2)));

__device__ __forceinline__ float fexp2(float x){ float r; asm("v_exp_f32 %0, %1":"=v"(r):"v"(x)); return r; }
__device__ __forceinline__ float frcp (float x){ float r; asm("v_rcp_f32 %0, %1":"=v"(r):"v"(x)); return r; }

// DPP helpers. row_ror:n = 0x120+n (16-lane ring; even n preserves parity).
template<int C> __device__ __forceinline__ int dppi(int x){
  return __builtin_amdgcn_update_dpp(0, x, C, 0xF, 0xF, true);
}
template<int C> __device__ __forceinline__ float dppf(float x){
  return __int_as_float(__builtin_amdgcn_update_dpp(0, __float_as_int(x), C, 0xF, 0xF, true));
}

// ---------------------------------------------------------------------------
// Kernel A (r7 layout): embW[v][slot][gate] = (b + x@W), pre-scaled per gate:
// i,f,o: -L2E (sigmoid via rcp(1+exp2)); g: +2L2E (tanh via 1-2rcp(1+exp2)).
// slot = (s+v)&7 bank rotation; pad state s=7 -> zeros. float4 per (v,s).
// ---------------------------------------------------------------------------
__global__ void embw_kernel(const float* __restrict__ emb, const float* __restrict__ W,
                            const float* __restrict__ b, float* __restrict__ embw){
  int v = blockIdx.x, j = threadIdx.x;          // j 0..31
  int s = j >> 2, gate = j & 3;
  float val = 0.0f;
  if (s < STATEN) {
    int col = gate*STATEN + s;
    val = b[col];
    #pragma unroll
    for (int e = 0; e < EMBEDN; ++e) val = fmaf(emb[v*EMBEDN+e], W[e*28+col], val);
    val *= (gate == 2) ? (2.0f*L2E) : (-L2E);
  }
  embw[v*32 + ((s+v)&7)*4 + gate] = val;
}

// ---------------------------------------------------------------------------
// Kernel B: lean 8-chain wave. 512 blocks x 64 thr; wave = 4 DPP rows x 2
// parity-interleaved chains = 8 chains. Lane (row, q=parity, s=pos>>1) owns
// ALL FOUR gates of state s for chain row*2+q -> cell update lane-local,
// NO mid-gate cross-lane exchanges on the serial path (the r14 path's ~40cy
// DPP segment removed; r8 tested this shape but confounded it with Pade's
// +100 instr — this keeps r3's exp2 algebra and r14's lean flush/ring).
// h-broadcast: 7 parity-preserving row_ror DPPs; sigma-permuted, pre-scaled
// U in registers; C tracked in 2*L2E*c domain.
// Flush: 64 lanes = 8 chains x 8 timesteps; lane (chf=L>>3, tq=L&7) does one
// full 10-col softmax per octet, staged branch-free across the 8 steps,
// reading the natural-order h-ring (no sigma on Wd). No softmax max-sub
// (r14-validated: logits bounded). 2-slot ring, same-wave in-order, no
// barriers in the loop.
// ---------------------------------------------------------------------------
__global__ void __launch_bounds__(64,1)
lstm_kernel(const int* __restrict__ tokens, const float* __restrict__ embw,
            const float* __restrict__ U, const float* __restrict__ Wd,
            const float* __restrict__ bdv, float* __restrict__ out){
  __shared__ float embW_s[VOCABN*32];   // 12.8 KB (slot-swizzled float4 rows)
  __shared__ int   tok_s[8*520];        // 16.6 KB (+pads for over-read)
  __shared__ float hring[2*8*64];       // 4 KB: [slot2][u8][ch8][state8]

  const int L = threadIdx.x;
  const int b0 = blockIdx.x*8;

  for (int i=L;i<VOCABN*8;i+=64) ((float4*)embW_s)[i]=((const float4*)embw)[i];
  for (int i=L;i<8*128;i+=64){ int r=i>>7,c4=i&127;
    int4 v=((const int4*)(tokens+(size_t)(b0+r)*SEQT))[c4];
    *((int4*)&tok_s[r*520+c4*4])=v; }
  if (L<8){ tok_s[L*520+512]=0; tok_s[L*520+513]=0; tok_s[L*520+514]=0; }
  __syncthreads();

  const int pos=L&15, row=L>>4, s=pos>>1, q=pos&1;
  const int ch = row*2 + q;                 // recurrence chain, 0..7

  // sigma discovery: push own state id through the exact broadcast net
  int sg[8];
  sg[0]=s;
  sg[1]=dppi<0x122>(s); sg[2]=dppi<0x124>(s); sg[3]=dppi<0x126>(s);
  sg[4]=dppi<0x128>(s); sg[5]=dppi<0x12A>(s); sg[6]=dppi<0x12C>(s); sg[7]=dppi<0x12E>(s);

  // recurrent weights: per h-term k, packed {i,f} and {g,o} cols of own
  // state s; pre-permuted by sigma; pre-scaled (-L2E / +2L2E).
  v2f Uif[8], Ugo[8];
  #pragma unroll
  for (int k=0;k<8;++k){
    int sk=sg[k]; bool vld=(sk<STATEN)&&(s<STATEN);
    Uif[k].x = vld ? U[sk*28 + 0*7 + s]*(-L2E)     : 0.0f;
    Uif[k].y = vld ? U[sk*28 + 1*7 + s]*(-L2E)     : 0.0f;
    Ugo[k].x = vld ? U[sk*28 + 2*7 + s]*(2.0f*L2E) : 0.0f;
    Ugo[k].y = vld ? U[sk*28 + 3*7 + s]*(-L2E)     : 0.0f;
  }

  // flush assignment: lane -> (chain chf, timestep-in-octet tq), all 10 cols
  const int chf = L>>3, tq = L&7;
  float Wdf[7][10], bdf[10];
  #pragma unroll
  for (int k=0;k<7;++k)
    #pragma unroll
    for (int o=0;o<OUTN;++o) Wdf[k][o] = Wd[k*10+o]*L2E;
  #pragma unroll
  for (int o=0;o<OUTN;++o) bdf[o]=bdv[o]*L2E;

  const int* trow=&tok_s[ch*520];
  float* outp = out + ((size_t)(b0+chf)*SEQT + tq)*OUTN;

  const int hoff = ch*8 + s;               // ring write: distinct word/lane
  const int roff = tq*64 + chf*8;          // ring read: 8 contiguous floats

  float hc[8], lg[10], ee[10];
  float rs=0.0f;

  // depth-1 prefetch queues (LDS)
  int tok_next = trow[1];
  float4 pf0 = *(const float4*)&embW_s[trow[0]*32 + (((s+trow[0])&7)<<2)];
  float Cc=0.0f, h=0.0f;

  for (int m=0;m<64;++m){
    const int* trm = trow + m*8;
    float* wv = hring + (m&1)*512;                   // write slot (m&1)
    const float* rv = hring + ((m+1)&1)*512 + roff;  // read slot of octet m-1
    #pragma unroll
    for (int u=0;u<8;++u){
      // prefetch: token t+2 (imm offset), embW row t+1
      int tokN = trm[u+2];
      float4 pfN = *(const float4*)&embW_s[tok_next*32 + (((s+tok_next)&7)<<2)];

      // broadcast h_{t-1} across the 8-lane chain (7 parity-preserving DPPs)
      float r0=h;
      float r1=dppf<0x122>(h), r2=dppf<0x124>(h), r3=dppf<0x126>(h);
      float r4=dppf<0x128>(h), r5=dppf<0x12A>(h), r6=dppf<0x12C>(h), r7=dppf<0x12E>(h);

      // z: 4 gate cols as 2x v2f packed trees (pre-scaled)
      v2f zif = {pf0.x, pf0.y}, zgo = {pf0.z, pf0.w};
      v2f a01 = __builtin_elementwise_fma((v2f){r1,r1},Uif[1],
                __builtin_elementwise_fma((v2f){r0,r0},Uif[0],zif));
      v2f a23 = __builtin_elementwise_fma((v2f){r3,r3},Uif[3],(v2f){r2,r2}*Uif[2]);
      v2f a45 = __builtin_elementwise_fma((v2f){r5,r5},Uif[5],(v2f){r4,r4}*Uif[4]);
      v2f a67 = __builtin_elementwise_fma((v2f){r7,r7},Uif[7],(v2f){r6,r6}*Uif[6]);
      zif = (a01+a23)+(a45+a67);
      v2f b01 = __builtin_elementwise_fma((v2f){r1,r1},Ugo[1],
                __builtin_elementwise_fma((v2f){r0,r0},Ugo[0],zgo));
      v2f b23 = __builtin_elementwise_fma((v2f){r3,r3},Ugo[3],(v2f){r2,r2}*Ugo[2]);
      v2f b45 = __builtin_elementwise_fma((v2f){r5,r5},Ugo[5],(v2f){r4,r4}*Ugo[4]);
      v2f b67 = __builtin_elementwise_fma((v2f){r7,r7},Ugo[7],(v2f){r6,r6}*Ugo[6]);
      zgo = (b01+b23)+(b45+b67);

      // gates, all lane-local (exp2 algebra, r3-validated):
      float gi = frcp(1.0f+fexp2(zif.x));             // sigmoid(zi)
      float gf = frcp(1.0f+fexp2(zif.y));             // sigmoid(zf)
      float rg = frcp(1.0f+fexp2(zgo.x));             // for tanh(zg)
      float go = frcp(1.0f+fexp2(zgo.y));             // sigmoid(zo)
      float gg_s = __builtin_fmaf(rg,-4.0f*L2E,2.0f*L2E); // 2L2E*tanh(zg)
      Cc = __builtin_fmaf(gf, Cc, gi*gg_s);           // 2L2E*c domain
      float rcpC = frcp(1.0f+fexp2(Cc));
      h = __builtin_fmaf(-2.0f*go, rcpC, go);         // h = o*tanh(c)

      wv[u*64 + hoff] = h;                            // publish h_t

      // ---- staged flush of octet m-1 (reads ring slot ((m+1)&1)) ----
      if (u==0){
        float4 a = *(const float4*)rv;
        float4 bq = *(const float4*)(rv+4);
        hc[0]=a.x; hc[1]=a.y; hc[2]=a.z; hc[3]=a.w;
        hc[4]=bq.x; hc[5]=bq.y; hc[6]=bq.z; hc[7]=bq.w;  // hc[7] unused
      }
      if (u==1){
        #pragma unroll
        for (int o=0;o<4;++o){ float a=bdf[o];
          #pragma unroll
          for (int k=0;k<7;++k) a=__builtin_fmaf(hc[k],Wdf[k][o],a);
          lg[o]=a; } }
      if (u==2){
        #pragma unroll
        for (int o=4;o<8;++o){ float a=bdf[o];
          #pragma unroll
          for (int k=0;k<7;++k) a=__builtin_fmaf(hc[k],Wdf[k][o],a);
          lg[o]=a; } }
      if (u==3){
        #pragma unroll
        for (int o=8;o<OUTN;++o){ float a=bdf[o];
          #pragma unroll
          for (int k=0;k<7;++k) a=__builtin_fmaf(hc[k],Wdf[k][o],a);
          lg[o]=a; } }
      if (u==4){
        ee[0]=fexp2(lg[0]); ee[1]=fexp2(lg[1]); ee[2]=fexp2(lg[2]);
        ee[3]=fexp2(lg[3]); ee[4]=fexp2(lg[4]); }     // no max-sub: bounded
      if (u==5){
        ee[5]=fexp2(lg[5]); ee[6]=fexp2(lg[6]); ee[7]=fexp2(lg[7]);
        ee[8]=fexp2(lg[8]); ee[9]=fexp2(lg[9]); }
      if (u==6){
        float sm=(((ee[0]+ee[1])+(ee[2]+ee[3]))+((ee[4]+ee[5])+(ee[6]+ee[7])))
                 +(ee[8]+ee[9]);
        rs=frcp(sm); }
      if (u==7){
        if (m>=1){
          float2* op=(float2*)outp;
          op[0]=make_float2(ee[0]*rs,ee[1]*rs);
          op[1]=make_float2(ee[2]*rs,ee[3]*rs);
          op[2]=make_float2(ee[4]*rs,ee[5]*rs);
          op[3]=make_float2(ee[6]*rs,ee[7]*rs);
          op[4]=make_float2(ee[8]*rs,ee[9]*rs);
          outp += 8*OUTN;
        } }

      pf0=pfN; tok_next=tokN;
    }
  }

  // ---- epilogue: flush octet 63 (ring slot 1) ----
  {
    const float* rv = hring + 512 + roff;   // slot (63&1)=1
    float4 a = *(const float4*)rv;
    float4 bq = *(const float4*)(rv+4);
    hc[0]=a.x; hc[1]=a.y; hc[2]=a.z; hc[3]=a.w;
    hc[4]=bq.x; hc[5]=bq.y; hc[6]=bq.z;
    #pragma unroll
    for (int o=0;o<OUTN;++o){ float aa=bdf[o];
      #pragma unroll
      for (int k=0;k<7;++k) aa=__builtin_fmaf(hc[k],Wdf[k][o],aa);
      lg[o]=aa; }
    float e0=fexp2(lg[0]), e1=fexp2(lg[1]), e2=fexp2(lg[2]), e3=fexp2(lg[3]),
          e4=fexp2(lg[4]), e5=fexp2(lg[5]), e6=fexp2(lg[6]), e7=fexp2(lg[7]),
          e8=fexp2(lg[8]), e9=fexp2(lg[9]);
    float sm=(((e0+e1)+(e2+e3))+((e4+e5)+(e6+e7)))+(e8+e9);
    float r=frcp(sm);
    float2* op=(float2*)outp;
    op[0]=make_float2(e0*r,e1*r);
    op[1]=make_float2(e2*r,e3*r);
    op[2]=make_float2(e4*r,e5*r);
    op[3]=make_float2(e6*r,e7*r);
    op[4]=make_float2(e8*r,e9*r);
  }
}

// ---------------------------------------------------------------------------
// inputs: 0 tokens 1 emb 2 W 3 U 4 b 5 Wd 6 bd ; out f32 B*T*10.
// d_ws: 12800 B for the pre-scaled embW table (rewritten every call).
// ---------------------------------------------------------------------------
extern "C" void kernel_launch(void* const* d_in, const int* in_sizes, int n_in,
                              void* d_out, int out_size, void* d_ws, size_t ws_size,
                              hipStream_t stream) {
  const int*   tokens = (const int*)d_in[0];
  const float* emb    = (const float*)d_in[1];
  const float* W      = (const float*)d_in[2];
  const float* U      = (const float*)d_in[3];
  const float* b      = (const float*)d_in[4];
  const float* Wd     = (const float*)d_in[5];
  const float* bd     = (const float*)d_in[6];
  float* outp = (float*)d_out;
  float* embw = (float*)d_ws;

  embw_kernel<<<dim3(VOCABN), dim3(32), 0, stream>>>(emb, W, b, embw);
  lstm_kernel<<<dim3(BATCHN/8), dim3(64), 0, stream>>>(tokens, embw, U, Wd, bd, outp);
}

// Round 19
// 78.834 us; speedup vs baseline: 1.3709x; 1.3709x over previous
//
#include <hip/hip_runtime.h>

// Problem constants (match reference)
#define VOCABN 100
#define EMBEDN 16
#define STATEN 7
#define OUTN   10
#define BATCHN 4096
#define SEQT   512
#define L2E 1.44269504088896340736f

typedef float v2f __attribute__((ext_vector_type(2)));

__device__ __forceinline__ float fexp2(float x){ float r; asm("v_exp_f32 %0, %1":"=v"(r):"v"(x)); return r; }
__device__ __forceinline__ float frcp (float x){ float r; asm("v_rcp_f32 %0, %1":"=v"(r):"v"(x)); return r; }

// DPP helpers. row_ror:n = 0x120+n (16-lane ring, parity-preserving for even n);
// quad_perm [1,0,3,2] = 0xB1 (parity-partner exchange).
template<int C> __device__ __forceinline__ int dppi(int x){
  return __builtin_amdgcn_update_dpp(0, x, C, 0xF, 0xF, true);
}
template<int C> __device__ __forceinline__ float dppf(float x){
  return __int_as_float(__builtin_amdgcn_update_dpp(0, __float_as_int(x), C, 0xF, 0xF, true));
}

// ---------------------------------------------------------------------------
// Kernel A (r14): embW2[v][pos] = pre-scaled gate pre-activations, pos=s*2+p.
// p0 -> (i,f), p1 -> (g,o). Scales i,f,o: -L2E; g: +2L2E. Pad s=7 -> 0.
// ---------------------------------------------------------------------------
__global__ void embw_kernel(const float* __restrict__ emb, const float* __restrict__ W,
                            const float* __restrict__ b, float* __restrict__ embw){
  int v = blockIdx.x, j = threadIdx.x;          // j 0..31
  int pos = j >> 1, g2 = j & 1;
  int s = pos >> 1, p = pos & 1, gate = p*2 + g2;
  float val = 0.0f;
  if (s < STATEN) {
    int col = gate*STATEN + s;
    val = b[col];
    #pragma unroll
    for (int e = 0; e < EMBEDN; ++e) val = fmaf(emb[v*EMBEDN+e], W[e*28+col], val);
    val *= (gate == 2) ? (2.0f*L2E) : (-L2E);
  }
  embw[v*32 + pos*2 + g2] = val;
}

// ---------------------------------------------------------------------------
// Kernel B: EXACT r14 datapath (validated 90us, absmax 4.88e-4) with HAND-
// SCHEDULED latency windows — the r18 finding is wall = issue + path with
// ~zero overlap, i.e. the compiler does not hoist the (independent) flush
// block into the two ~80cy transcendental-latency windows of the gate chain.
// Changes (scheduling only, zero arithmetic change):
//  GAP1: the staged-flush block now sits BETWEEN the gate exp2 issues and
//        their rcp uses (fills the exp2(zA/zB) result-latency window).
//  GAP2: the prefetch ds_reads (embW row, token) now sit BETWEEN exp2(Cc)
//        and rcp(1+eC); queue deepened to depth-2 (pf0/pf1, tkA/tkB) so the
//        later issue point still leaves ~2 steps (~800cy) before use.
// ---------------------------------------------------------------------------
__global__ void __launch_bounds__(64,1)
lstm_kernel(const int* __restrict__ tokens, const float* __restrict__ embw,
            const float* __restrict__ U, const float* __restrict__ Wd,
            const float* __restrict__ bdv, float* __restrict__ out){
  __shared__ float embW_s[VOCABN*32];   // 12.8 KB
  __shared__ int   tok_s[4*520];        // 8.3 KB (+pads for over-read)
  __shared__ float hbuf[2*8*48 + 64];   // 3.3 KB: 2 slots x [u8][48] + dummy

  const int L = threadIdx.x;
  const int b0 = blockIdx.x*4;

  for (int i=L;i<VOCABN*8;i+=64) ((float4*)embW_s)[i]=((const float4*)embw)[i];
  for (int i=L;i<512;i+=64){ int r=i>>7,c4=i&127;
    int4 v=((const int4*)(tokens+(size_t)(b0+r)*SEQT))[c4];
    *((int4*)&tok_s[r*520+c4*4])=v; }
  if (L<4){ tok_s[L*520+512]=0; tok_s[L*520+513]=0;
            tok_s[L*520+514]=0; tok_s[L*520+515]=0; }
  __syncthreads();

  const int pos=L&15, ch=L>>4, s=pos>>1, p=pos&1;
  const int pos2=pos*2;

  // sigma discovery: run own state id through the exact broadcast net
  int sg[8];
  sg[0]=s;
  sg[1]=dppi<0x122>(s); sg[2]=dppi<0x124>(s); sg[3]=dppi<0x126>(s);
  sg[4]=dppi<0x128>(s); sg[5]=dppi<0x12A>(s); sg[6]=dppi<0x12C>(s); sg[7]=dppi<0x12E>(s);

  // recurrent weights: packed {colA,colB}, pre-permuted by sigma, pre-scaled
  v2f Ucp[8];
  {
    const int gA=p*2, gB=p*2+1;
    const float sA = (gA==2)?(2.0f*L2E):(-L2E);
    const float sB = (gB==2)?(2.0f*L2E):(-L2E);
    #pragma unroll
    for (int k=0;k<8;++k){
      int sk=sg[k]; bool vld=(sk<STATEN)&&(s<STATEN);
      Ucp[k].x = vld ? U[sk*28+gA*7+s]*sA : 0.0f;
      Ucp[k].y = vld ? U[sk*28+gB*7+s]*sB : 0.0f;
    }
  }
  // dense weights, NATURAL state order (ring h unpermuted), L2E-scaled
  float Wdc[8][5], bdr[5];
  #pragma unroll
  for (int k=0;k<8;++k)
    #pragma unroll
    for (int o=0;o<5;++o) Wdc[k][o] = (k<STATEN)? Wd[k*10+p*5+o]*L2E : 0.0f;
  #pragma unroll
  for (int o=0;o<5;++o) bdr[o]=bdv[p*5+o]*L2E;

  const int* trow=&tok_s[ch*520];
  float* outp = out + ((size_t)(b0+ch)*SEQT + s)*OUTN + p*5;  // s doubles as flush-timestep

  // h-ring lane addresses: even lanes carry the real h; odd lanes write a
  // distinct dummy strip (bank-clean).
  const int loff = p ? (2*8*48 + L) : (ch*8 + s);
  const int roff = s*48 + ch*8;            // flush read: [tq=s][ch*8..+7]

  float hc[8], lg[5], ee[5];
  float smq=0.0f, rs=0.0f;

  // depth-2 prefetch queues. State at top of step t:
  //   pf0=row(t), pf1=row(t+1), tkA=tok(t+2), tkB=tok(t+3).
  int tkA = trow[2];
  int tkB = trow[3];
  v2f pf0 = *(const v2f*)&embW_s[trow[0]*32 + pos2];
  v2f pf1 = *(const v2f*)&embW_s[trow[1]*32 + pos2];
  float Cc=0.0f, h=0.0f;

  for (int m=0;m<64;++m){
    float* wv = hbuf + (m&1)*384 + loff;             // write slot (m&1)
    const float* rv = hbuf + ((m+1)&1)*384 + roff;   // read slot of octet m-1
    #pragma unroll
    for (int u=0;u<8;++u){
      const int t = m*8+u;

      // broadcast h_{t-1} across the 16-lane chain (depth-1 DPP net)
      float r0=h;
      float r1=dppf<0x122>(h), r2=dppf<0x124>(h), r3=dppf<0x126>(h);
      float r4=dppf<0x128>(h), r5=dppf<0x12A>(h), r6=dppf<0x12C>(h), r7=dppf<0x12E>(h);

      // z = embW'[tok] + h @ U'  (v2f packed tree — r5-validated)
      v2f z01=__builtin_elementwise_fma((v2f){r1,r1},Ucp[1],
              __builtin_elementwise_fma((v2f){r0,r0},Ucp[0],pf0));
      v2f z23=__builtin_elementwise_fma((v2f){r3,r3},Ucp[3],(v2f){r2,r2}*Ucp[2]);
      v2f z45=__builtin_elementwise_fma((v2f){r5,r5},Ucp[5],(v2f){r4,r4}*Ucp[4]);
      v2f z67=__builtin_elementwise_fma((v2f){r7,r7},Ucp[7],(v2f){r6,r6}*Ucp[6]);
      v2f zv=(z01+z23)+(z45+z67);

      // gate exp2 ISSUE (results consumed after GAP1)
      float eA = fexp2(zv.x);
      float eB = fexp2(zv.y);

      // ================= GAP1: staged flush of octet m-1 =================
      // (independent of eA/eB — fills the exp2 result-latency window)
      if (u==0){
        float4 a = *(const float4*)rv;
        float4 bq = *(const float4*)(rv+4);
        hc[0]=a.x; hc[1]=a.y; hc[2]=a.z; hc[3]=a.w;
        hc[4]=bq.x; hc[5]=bq.y; hc[6]=bq.z; hc[7]=bq.w;  // hc[7]*Wdc[7]=0
      }
      if (u==1){
        float a0=bdr[0], a1=bdr[1];
        #pragma unroll
        for (int k=0;k<8;++k){ a0=__builtin_fmaf(hc[k],Wdc[k][0],a0);
                               a1=__builtin_fmaf(hc[k],Wdc[k][1],a1); }
        lg[0]=a0; lg[1]=a1; }
      if (u==2){
        float a2=bdr[2], a3=bdr[3];
        #pragma unroll
        for (int k=0;k<8;++k){ a2=__builtin_fmaf(hc[k],Wdc[k][2],a2);
                               a3=__builtin_fmaf(hc[k],Wdc[k][3],a3); }
        lg[2]=a2; lg[3]=a3; }
      if (u==3){
        float a4=bdr[4];
        #pragma unroll
        for (int k=0;k<8;++k) a4=__builtin_fmaf(hc[k],Wdc[k][4],a4);
        lg[4]=a4; }
      if (u==4){
        ee[0]=fexp2(lg[0]); ee[1]=fexp2(lg[1]); ee[2]=fexp2(lg[2]);
        ee[3]=fexp2(lg[3]); ee[4]=fexp2(lg[4]); }       // no max-sub: bounded
      if (u==5){
        smq=((ee[0]+ee[1])+(ee[2]+ee[3]))+ee[4]; }
      if (u==6){
        rs=frcp(smq + dppf<0xB1>(smq)); }               // combine with partner
      if (u==7){
        if (m>=1){
          outp[0]=ee[0]*rs; outp[1]=ee[1]*rs; outp[2]=ee[2]*rs;
          outp[3]=ee[3]*rs; outp[4]=ee[4]*rs;
          outp += 8*OUTN;
        } }
      // ===================================================================

      // gate rcp (uses eA/eB, now ~GAP1 later) + mid-gate exchanges
      float gA=frcp(1.0f+eA);
      float gB=frcp(1.0f+eB);
      float gg_s=__builtin_fmaf(gA,-4.0f*L2E,2.0f*L2E); // 2L2E*tanh(zg) on p1
      float gg_x=dppf<0xB1>(gg_s);                      // p0 <- p1
      float go_x=dppf<0xB1>(gB);                        // p0 <- p1's o
      Cc=__builtin_fmaf(gB,Cc,gA*gg_x);                 // valid on p0 (2L2E*c)
      float eC=fexp2(Cc);                               // ISSUE (consumed after GAP2)

      // ============ GAP2: prefetch issue (fills exp2(Cc) window) ==========
      v2f pf2 = *(const v2f*)&embW_s[tkA*32 + pos2];    // row(t+2)
      int tkC = trow[t+4];                              // tok(t+4), pads at 512..515
      // ===================================================================

      float rcpC=frcp(1.0f+eC);                         // valid on p0
      float rcpC_x=dppf<0xB1>(rcpC);                    // p1 <- p0
      float go_u = p ? gB     : go_x;
      float rc_u = p ? rcpC_x : rcpC;
      h=__builtin_fmaf(-2.0f*go_u, rc_u, go_u);         // h = o*tanh(c)

      wv[u*48] = h;                                     // publish h_t (imm offset)

      pf0=pf1; pf1=pf2; tkA=tkB; tkB=tkC;
    }
  }

  // ---- epilogue: flush octet 63 (ring slot 1) ----
  {
    const float* rv = hbuf + 384 + roff;   // (63&1)=1
    float4 a = *(const float4*)rv;
    float4 bq = *(const float4*)(rv+4);
    hc[0]=a.x; hc[1]=a.y; hc[2]=a.z; hc[3]=a.w;
    hc[4]=bq.x; hc[5]=bq.y; hc[6]=bq.z; hc[7]=bq.w;
    #pragma unroll
    for (int o=0;o<5;++o){ float aa=bdr[o];
      #pragma unroll
      for (int k=0;k<8;++k) aa=__builtin_fmaf(hc[k],Wdc[k][o],aa);
      lg[o]=aa; }
    float e0=fexp2(lg[0]), e1=fexp2(lg[1]), e2=fexp2(lg[2]),
          e3=fexp2(lg[3]), e4=fexp2(lg[4]);
    float sm=((e0+e1)+(e2+e3))+e4;
    float r=frcp(sm + dppf<0xB1>(sm));
    outp[0]=e0*r; outp[1]=e1*r; outp[2]=e2*r; outp[3]=e3*r; outp[4]=e4*r;
  }
}

// ---------------------------------------------------------------------------
// inputs: 0 tokens 1 emb 2 W 3 U 4 b 5 Wd 6 bd ; out f32 B*T*10.
// d_ws: 12800 B for the pre-scaled embW table (rewritten every call).
// ---------------------------------------------------------------------------
extern "C" void kernel_launch(void* const* d_in, const int* in_sizes, int n_in,
                              void* d_out, int out_size, void* d_ws, size_t ws_size,
                              hipStream_t stream) {
  const int*   tokens = (const int*)d_in[0];
  const float* emb    = (const float*)d_in[1];
  const float* W      = (const float*)d_in[2];
  const float* U      = (const float*)d_in[3];
  const float* b      = (const float*)d_in[4];
  const float* Wd     = (const float*)d_in[5];
  const float* bd     = (const float*)d_in[6];
  float* outp = (float*)d_out;
  float* embw = (float*)d_ws;

  embw_kernel<<<dim3(VOCABN), dim3(32), 0, stream>>>(emb, W, b, embw);
  lstm_kernel<<<dim3(BATCHN/4), dim3(64), 0, stream>>>(tokens, embw, U, Wd, bd, outp);
}